// Round 1
// baseline (135.423 us; speedup 1.0000x reference)
//
#include <hip/hip_runtime.h>
#include <stdint.h>

#define CIN   128
#define COUT  256
#define HW    56
#define SP    3136      // 56*56
#define NIMG  32
#define NPIX  (NIMG*SP) // 100352
#define KTOT  (CIN*9)   // 1152
#define NSTEP 36        // KTOT/32

typedef unsigned short u16;
using bf16x8 = __attribute__((ext_vector_type(8))) short;   // 8 bf16 in 4 VGPRs
using f32x4  = __attribute__((ext_vector_type(4))) float;

__device__ __forceinline__ u16 sgn_bf16(float v) {
  return v > 0.f ? (u16)0x3F80 : (v < 0.f ? (u16)0xBF80 : (u16)0);
}

__device__ __forceinline__ void gl_lds16(const void* g, void* l) {
  __builtin_amdgcn_global_load_lds(
      (const __attribute__((address_space(1))) void*)g,
      (__attribute__((address_space(3))) void*)l, 16, 0, 0);
}

// ---- prepass: binarize + K-transpose weights: wT[o][q*128+c], q=kh*3+kw ----
__global__ void prep_w(const float* __restrict__ w, u16* __restrict__ wT,
                       u16* __restrict__ zerob) {
  int idx = blockIdx.x * 256 + threadIdx.x;
  if (blockIdx.x == 0 && threadIdx.x < 128) zerob[threadIdx.x] = 0;
  if (idx >= COUT * KTOT) return;
  int o = idx / KTOT;
  int r = idx - o * KTOT;
  int q = r >> 7;        // 0..8
  int c = r & 127;
  float v = w[(size_t)(o * CIN + c) * 9 + q];
  wT[idx] = sgn_bf16(v);
}

// ---- prepass: binarize + NCHW->NHWC transpose of x into bf16 ----
__global__ void prep_x(const float* __restrict__ x, u16* __restrict__ xt) {
  __shared__ u16 tile[128][34];
  int b = blockIdx.x;            // 32 n * 98 s-chunks
  int n = b / 98;
  int s0 = (b - n * 98) * 32;
  int t = threadIdx.x;
  int tx = t & 31, ty = t >> 5;  // ty in [0,8)
  const float* xb = x + (size_t)n * CIN * SP;
#pragma unroll
  for (int i = 0; i < 16; ++i) {
    int c = ty + (i << 3);                      // 0..127
    float v = xb[(size_t)c * SP + s0 + tx];
    tile[c][tx] = sgn_bf16(v);
  }
  __syncthreads();
  int tc = t & 127, tys = t >> 7;               // tys in {0,1}
  u16* xtb = xt + (size_t)(n * SP + s0) * CIN;
#pragma unroll
  for (int i = 0; i < 16; ++i) {
    int s = tys + (i << 1);                     // 0..31
    xtb[(size_t)s * CIN + tc] = tile[tc][s];
  }
}

// ---- main: implicit-GEMM binarized conv, 128x128 tile, bf16 MFMA ----
__global__ __launch_bounds__(256) void conv_mfma(
    const u16* __restrict__ wT, const u16* __restrict__ xt,
    const float* __restrict__ bias, const u16* __restrict__ zerob,
    float* __restrict__ out) {
  __shared__ u16 As[2][4096];   // [128 rows Cout][32 k]
  __shared__ u16 Bs[2][4096];   // [128 rows pixel][32 k]

  const int bid = blockIdx.x;
  const int mt = bid & 1;        // Cout tile (0,1)
  const int nt = bid >> 1;       // pixel tile (0..783)
  const int t  = threadIdx.x;
  const int wv = t >> 6;
  const int ln = t & 63;
  const int pb = nt << 7;

  // staging lane geometry: each wave stages rows [wv*32, wv*32+32), two 16-row halves
  const int srow  = ln >> 2;     // 0..15
  const int chunk = ln & 3;      // 8 bf16 each

  const u16* aBase = wT + (size_t)((mt << 7) + (wv << 5) + srow) * KTOT + (chunk << 3);

  const int p0 = pb + (wv << 5) + srow;
  const int p1 = p0 + 16;
  const int h0 = (p0 % SP) / HW, w0 = p0 % HW;
  const int h1 = (p1 % SP) / HW, w1 = p1 % HW;
  const u16* xBase0 = xt + (size_t)p0 * CIN + (chunk << 3);
  const u16* xBase1 = xt + (size_t)p1 * CIN + (chunk << 3);

  auto stage = [&](int buf, int s) {
    const int q  = s >> 2;                 // 0..8 = kh*3+kw
    const int c0 = (s & 3) << 5;           // channel base 0..96
    const int qd = q / 3;
    const int dh = qd - 1;
    const int dw = (q - qd * 3) - 1;
    const int doff = dh * HW + dw;
    // A tile
    u16* ldsA = &As[buf][(wv << 5) << 5];  // wave-uniform
    const u16* ga = aBase + (s << 5);
    gl_lds16(ga,              ldsA);
    gl_lds16(ga + 16 * KTOT,  ldsA + 16 * 32);
    // B tile (im2col gather; invalid -> zero buffer)
    u16* ldsB = &Bs[buf][(wv << 5) << 5];
    bool v0 = ((unsigned)(h0 + dh) < HW) && ((unsigned)(w0 + dw) < HW);
    bool v1 = ((unsigned)(h1 + dh) < HW) && ((unsigned)(w1 + dw) < HW);
    const u16* gb0 = v0 ? (xBase0 + (size_t)doff * CIN + c0) : zerob;
    const u16* gb1 = v1 ? (xBase1 + (size_t)doff * CIN + c0) : zerob;
    gl_lds16(gb0, ldsB);
    gl_lds16(gb1, ldsB + 16 * 32);
  };

  f32x4 acc[4][4];
#pragma unroll
  for (int i = 0; i < 4; ++i)
#pragma unroll
    for (int j = 0; j < 4; ++j) acc[i][j] = (f32x4){0.f, 0.f, 0.f, 0.f};

  const int wm = wv >> 1, wn = wv & 1;
  const int lr = ln & 15, kg = ln >> 4;
  const int aoff = ((wm << 6) + lr) << 5;
  const int boff = ((wn << 6) + lr) << 5;
  const int koff = kg << 3;

  stage(0, 0);
  for (int s = 0; s < NSTEP; ++s) {
    __syncthreads();                       // drains vmcnt -> buf s&1 ready
    if (s + 1 < NSTEP) stage((s + 1) & 1, s + 1);
    const int buf = s & 1;
    bf16x8 af[4], bfr[4];
#pragma unroll
    for (int i = 0; i < 4; ++i)
      af[i] = *(const bf16x8*)&As[buf][aoff + (i << 9) + koff];
#pragma unroll
    for (int j = 0; j < 4; ++j)
      bfr[j] = *(const bf16x8*)&Bs[buf][boff + (j << 9) + koff];
#pragma unroll
    for (int i = 0; i < 4; ++i)
#pragma unroll
      for (int j = 0; j < 4; ++j)
        acc[i][j] = __builtin_amdgcn_mfma_f32_16x16x32_bf16(af[i], bfr[j], acc[i][j], 0, 0, 0);
  }

  // epilogue: C[m][n] -> out[nimg][m][sp], + sign(bias[m])
  const int mBase = (mt << 7) + (wm << 6);
  const int nBase = pb + (wn << 6);
#pragma unroll
  for (int j = 0; j < 4; ++j) {
    const int np = nBase + (j << 4) + lr;
    const int nimg = np / SP;
    const int sp = np - nimg * SP;
    float* op = out + (size_t)nimg * COUT * SP + sp;
#pragma unroll
    for (int i = 0; i < 4; ++i) {
      const int m0 = mBase + (i << 4) + (kg << 2);
#pragma unroll
      for (int r = 0; r < 4; ++r) {
        const int m = m0 + r;
        float bv = bias[m];
        float sb = bv > 0.f ? 1.f : (bv < 0.f ? -1.f : 0.f);
        op[(size_t)m * SP] = acc[i][j][r] + sb;
      }
    }
  }
}

// ---- fallback if workspace is too small: direct conv (slow but correct) ----
__global__ void conv_naive(const float* __restrict__ x, const float* __restrict__ w,
                           const float* __restrict__ bias, float* __restrict__ out) {
  int idx = blockIdx.x * 256 + threadIdx.x;
  const int total = NIMG * COUT * SP;
  if (idx >= total) return;
  int sp = idx % SP;
  int o  = (idx / SP) % COUT;
  int n  = idx / (SP * COUT);
  int h = sp / HW, wx = sp - (sp / HW) * HW;
  float acc = 0.f;
  for (int c = 0; c < CIN; ++c) {
    const float* xp = x + (size_t)(n * CIN + c) * SP;
    const float* wp = w + (size_t)(o * CIN + c) * 9;
    for (int kh = 0; kh < 3; ++kh) {
      int hh = h + kh - 1;
      if ((unsigned)hh >= HW) continue;
      for (int kw = 0; kw < 3; ++kw) {
        int ww = wx + kw - 1;
        if ((unsigned)ww >= HW) continue;
        float xv = xp[hh * HW + ww];
        float wv = wp[kh * 3 + kw];
        float xs = xv > 0.f ? 1.f : (xv < 0.f ? -1.f : 0.f);
        float wsn = wv > 0.f ? 1.f : (wv < 0.f ? -1.f : 0.f);
        acc += xs * wsn;
      }
    }
  }
  float bv = bias[o];
  out[idx] = acc + (bv > 0.f ? 1.f : (bv < 0.f ? -1.f : 0.f));
}

extern "C" void kernel_launch(void* const* d_in, const int* in_sizes, int n_in,
                              void* d_out, int out_size, void* d_ws, size_t ws_size,
                              hipStream_t stream) {
  const float* x    = (const float*)d_in[0];
  const float* w    = (const float*)d_in[1];
  const float* bias = (const float*)d_in[2];
  float* out = (float*)d_out;

  const size_t need = (size_t)1048576 + (size_t)NPIX * CIN * 2;  // ~26.7 MB
  if (ws_size >= need) {
    u16* zerob = (u16*)d_ws;                         // 256 B zeros
    u16* wT    = (u16*)((char*)d_ws + 512);          // 256x1152 bf16
    u16* xt    = (u16*)((char*)d_ws + 1048576);      // NHWC bf16
    prep_w<<<(COUT * KTOT + 255) / 256, 256, 0, stream>>>(w, wT, zerob);
    prep_x<<<NIMG * 98, 256, 0, stream>>>(x, xt);
    conv_mfma<<<2 * (NPIX / 128), 256, 0, stream>>>(wT, xt, bias, zerob, out);
  } else {
    const int total = NIMG * COUT * SP;
    conv_naive<<<(total + 255) / 256, 256, 0, stream>>>(x, w, bias, out);
  }
}

// Round 2
// 69.200 us; speedup vs baseline: 1.9570x; 1.9570x over previous
//
#include <hip/hip_runtime.h>
#include <stdint.h>

#define CIN   128
#define COUT  256
#define HW    56
#define SP    3136      // 56*56
#define NIMG  32
#define NPIX  (NIMG*SP) // 100352
#define KTOT  (CIN*9)   // 1152

typedef unsigned short u16;
typedef unsigned char  u8;
using i32x4 = __attribute__((ext_vector_type(4))) int;

__device__ __forceinline__ u8 sgn_i8(float v) {
  return v > 0.f ? (u8)1 : (v < 0.f ? (u8)0xFF : (u8)0);
}

__device__ __forceinline__ void gl_lds16(const void* g, void* l) {
  __builtin_amdgcn_global_load_lds(
      (const __attribute__((address_space(1))) void*)g,
      (__attribute__((address_space(3))) void*)l, 16, 0, 0);
}

// ---- prepass: binarize + K-transpose weights to i8: wT[o][q*128+c] ----
__global__ void prep_w(const float* __restrict__ w, u8* __restrict__ wT,
                       u8* __restrict__ zerob) {
  int idx = blockIdx.x * 256 + threadIdx.x;
  if (blockIdx.x == 0 && threadIdx.x < 64) ((uint32_t*)zerob)[threadIdx.x] = 0;
  if (idx >= COUT * KTOT) return;
  int o = idx / KTOT;
  int r = idx - o * KTOT;
  int q = r >> 7;
  int c = r & 127;
  wT[idx] = sgn_i8(w[(size_t)(o * CIN + c) * 9 + q]);
}

// ---- prepass: binarize + NCHW->NHWC transpose of x into i8 ----
__global__ void prep_x(const float* __restrict__ x, u8* __restrict__ xt) {
  __shared__ u8 tile[128][36];
  int b = blockIdx.x;            // 32 n * 98 s-chunks
  int n = b / 98;
  int s0 = (b - n * 98) * 32;
  int t = threadIdx.x;
  int tx = t & 31, ty = t >> 5;  // ty in [0,8)
  const float* xb = x + (size_t)n * CIN * SP;
#pragma unroll
  for (int i = 0; i < 16; ++i) {
    int c = ty + (i << 3);                      // 0..127
    tile[c][tx] = sgn_i8(xb[(size_t)c * SP + s0 + tx]);
  }
  __syncthreads();
  int s = t >> 3, cg = t & 7;                   // s 0..31, cg 0..7
  int c0 = cg << 4;
  uint32_t pk[4];
#pragma unroll
  for (int jj = 0; jj < 4; ++jj) {
    uint32_t a0 = tile[c0 + jj * 4 + 0][s];
    uint32_t a1 = tile[c0 + jj * 4 + 1][s];
    uint32_t a2 = tile[c0 + jj * 4 + 2][s];
    uint32_t a3 = tile[c0 + jj * 4 + 3][s];
    pk[jj] = a0 | (a1 << 8) | (a2 << 16) | (a3 << 24);
  }
  u8* dst = xt + (size_t)(n * SP + s0 + s) * CIN + c0;
  uint4 u; u.x = pk[0]; u.y = pk[1]; u.z = pk[2]; u.w = pk[3];
  *(uint4*)dst = u;
}

// ---- main: implicit-GEMM binarized conv, 128x128 tile, i8 MFMA, BK=128 ----
__global__ __launch_bounds__(256) void conv_mfma(
    const u8* __restrict__ wT, const u8* __restrict__ xt,
    const float* __restrict__ bias, const u8* __restrict__ zerob,
    float* __restrict__ out) {
  __shared__ u8 As[2][16384];   // [128 rows Cout][128 k] swizzled chunks
  __shared__ u8 Bs[2][16384];   // [128 rows pixel][128 k]

  const int bid = blockIdx.x;
  const int mt = bid & 1;        // Cout tile (0,1)
  const int nt = bid >> 1;       // pixel tile (0..783)
  const int t  = threadIdx.x;
  const int wv = t >> 6;
  const int ln = t & 63;
  const int pb = nt << 7;

  // ---- staging lane geometry: per gl_lds call a wave covers 8 rows x 128B ----
  const int sr  = ln >> 3;            // row-within-8 (== row&7 for all calls)
  const int ch  = ln & 7;             // physical dest chunk
  const int chs = ch ^ sr;            // pre-swizzled source chunk

  const u8* gA[4];
  const u8* gB[4];
  int hh[4], ww[4];
#pragma unroll
  for (int call = 0; call < 4; ++call) {
    const int row = call * 32 + wv * 8 + sr;         // 0..127
    gA[call] = wT + (size_t)((mt << 7) + row) * KTOT + (chs << 4);
    const int p = pb + row;
    const int s = p % SP;
    hh[call] = s / HW;
    ww[call] = s - (s / HW) * HW;
    gB[call] = xt + (size_t)p * CIN + (chs << 4);
  }

  // ---- fragment-read geometry (swizzled) ----
  const int wm = wv >> 1, wn = wv & 1;
  const int lr = ln & 15, kg = ln >> 4;
  const int xr = lr & 7;
  const int rdA0 = (((wm << 6) + lr) << 7) + ((kg ^ xr) << 4);
  const int rdA1 = (((wm << 6) + lr) << 7) + (((4 | kg) ^ xr) << 4);
  const int rdB0 = (((wn << 6) + lr) << 7) + ((kg ^ xr) << 4);
  const int rdB1 = (((wn << 6) + lr) << 7) + (((4 | kg) ^ xr) << 4);

  i32x4 acc[4][4];
#pragma unroll
  for (int i = 0; i < 4; ++i)
#pragma unroll
    for (int j = 0; j < 4; ++j) acc[i][j] = (i32x4){0, 0, 0, 0};

  auto stage = [&](int buf, int q) {
    const int dh = q / 3 - 1;           // compile-time after unroll
    const int dw = q - (q / 3) * 3 - 1;
    const int doff = (dh * HW + dw) * CIN;
#pragma unroll
    for (int call = 0; call < 4; ++call) {
      u8* ldsA = &As[buf][(call * 32 + wv * 8) << 7];  // wave-uniform
      gl_lds16(gA[call] + q * CIN, ldsA);
      bool ok = ((unsigned)(hh[call] + dh) < HW) && ((unsigned)(ww[call] + dw) < HW);
      const u8* src = ok ? (gB[call] + doff) : zerob;
      u8* ldsB = &Bs[buf][(call * 32 + wv * 8) << 7];
      gl_lds16(src, ldsB);
    }
  };

  stage(0, 0);
#pragma unroll
  for (int s = 0; s < 9; ++s) {
    __syncthreads();                    // drains vmcnt -> buf s&1 ready
    if (s + 1 < 9) stage((s + 1) & 1, s + 1);
    const int buf = s & 1;
#pragma unroll
    for (int kc = 0; kc < 2; ++kc) {
      i32x4 af[4], bfg[4];
#pragma unroll
      for (int i = 0; i < 4; ++i)
        af[i] = *(const i32x4*)&As[buf][(kc ? rdA1 : rdA0) + (i << 11)];
#pragma unroll
      for (int j = 0; j < 4; ++j)
        bfg[j] = *(const i32x4*)&Bs[buf][(kc ? rdB1 : rdB0) + (j << 11)];
#pragma unroll
      for (int i = 0; i < 4; ++i)
#pragma unroll
        for (int j = 0; j < 4; ++j)
          acc[i][j] = __builtin_amdgcn_mfma_i32_16x16x64_i8(af[i], bfg[j], acc[i][j], 0, 0, 0);
    }
  }

  // ---- epilogue: C[m][n] -> out[nimg][m][sp], + sign(bias[m]) ----
  const int mBase = (mt << 7) + (wm << 6);
  const int nBase = pb + (wn << 6);
#pragma unroll
  for (int j = 0; j < 4; ++j) {
    const int np = nBase + (j << 4) + lr;
    const int nimg = np / SP;
    const int sp = np - nimg * SP;
    float* op = out + (size_t)nimg * COUT * SP + sp;
#pragma unroll
    for (int i = 0; i < 4; ++i) {
      const int m0 = mBase + (i << 4) + (kg << 2);
#pragma unroll
      for (int r = 0; r < 4; ++r) {
        const int m = m0 + r;
        float bv = bias[m];
        float sb = bv > 0.f ? 1.f : (bv < 0.f ? -1.f : 0.f);
        op[(size_t)m * SP] = (float)acc[i][j][r] + sb;
      }
    }
  }
}

// ---- fallback if workspace is too small: direct conv (slow but correct) ----
__global__ void conv_naive(const float* __restrict__ x, const float* __restrict__ w,
                           const float* __restrict__ bias, float* __restrict__ out) {
  int idx = blockIdx.x * 256 + threadIdx.x;
  const int total = NIMG * COUT * SP;
  if (idx >= total) return;
  int sp = idx % SP;
  int o  = (idx / SP) % COUT;
  int n  = idx / (SP * COUT);
  int h = sp / HW, wx = sp - (sp / HW) * HW;
  float acc = 0.f;
  for (int c = 0; c < CIN; ++c) {
    const float* xp = x + (size_t)(n * CIN + c) * SP;
    const float* wp = w + (size_t)(o * CIN + c) * 9;
    for (int kh = 0; kh < 3; ++kh) {
      int hhh = h + kh - 1;
      if ((unsigned)hhh >= HW) continue;
      for (int kw = 0; kw < 3; ++kw) {
        int www = wx + kw - 1;
        if ((unsigned)www >= HW) continue;
        float xv = xp[hhh * HW + www];
        float wv = wp[kh * 3 + kw];
        float xs = xv > 0.f ? 1.f : (xv < 0.f ? -1.f : 0.f);
        float wsn = wv > 0.f ? 1.f : (wv < 0.f ? -1.f : 0.f);
        acc += xs * wsn;
      }
    }
  }
  float bv = bias[o];
  out[idx] = acc + (bv > 0.f ? 1.f : (bv < 0.f ? -1.f : 0.f));
}

extern "C" void kernel_launch(void* const* d_in, const int* in_sizes, int n_in,
                              void* d_out, int out_size, void* d_ws, size_t ws_size,
                              hipStream_t stream) {
  const float* x    = (const float*)d_in[0];
  const float* w    = (const float*)d_in[1];
  const float* bias = (const float*)d_in[2];
  float* out = (float*)d_out;

  const size_t need = (size_t)1048576 + (size_t)NPIX * CIN;  // ~13.9 MB
  if (ws_size >= need) {
    u8* zerob = (u8*)d_ws;                        // 256 B zeros
    u8* wT8   = (u8*)((char*)d_ws + 512);         // 256x1152 i8
    u8* xt8   = (u8*)((char*)d_ws + 1048576);     // NHWC i8
    prep_w<<<(COUT * KTOT + 255) / 256, 256, 0, stream>>>(w, wT8, zerob);
    prep_x<<<NIMG * 98, 256, 0, stream>>>(x, xt8);
    conv_mfma<<<2 * (NPIX / 128), 256, 0, stream>>>(wT8, xt8, bias, zerob, out);
  } else {
    const int total = NIMG * COUT * SP;
    conv_naive<<<(total + 255) / 256, 256, 0, stream>>>(x, w, bias, out);
  }
}

// Round 3
// 66.489 us; speedup vs baseline: 2.0368x; 1.0408x over previous
//
#include <hip/hip_runtime.h>
#include <stdint.h>

#define CIN   128
#define COUT  256
#define HW    56
#define SP    3136      // 56*56
#define NIMG  32
#define NPIX  (NIMG*SP) // 100352
#define KTOT  (CIN*9)   // 1152

typedef unsigned short u16;
typedef unsigned char  u8;
using i32x4 = __attribute__((ext_vector_type(4))) int;

__device__ __forceinline__ u8 sgn_i8(float v) {
  return v > 0.f ? (u8)1 : (v < 0.f ? (u8)0xFF : (u8)0);
}

__device__ __forceinline__ void gl_lds16(const void* g, void* l) {
  __builtin_amdgcn_global_load_lds(
      (const __attribute__((address_space(1))) void*)g,
      (__attribute__((address_space(3))) void*)l, 16, 0, 0);
}

// ---- prepass: binarize + K-transpose weights to i8: wT[o][q*128+c] ----
__global__ void prep_w(const float* __restrict__ w, u8* __restrict__ wT,
                       u8* __restrict__ zerob) {
  int idx = blockIdx.x * 256 + threadIdx.x;
  if (blockIdx.x == 0 && threadIdx.x < 64) ((uint32_t*)zerob)[threadIdx.x] = 0;
  if (idx >= COUT * KTOT) return;
  int o = idx / KTOT;
  int r = idx - o * KTOT;
  int q = r >> 7;
  int c = r & 127;
  wT[idx] = sgn_i8(w[(size_t)(o * CIN + c) * 9 + q]);
}

// ---- prepass: binarize + NCHW->NHWC transpose of x into i8 ----
__global__ void prep_x(const float* __restrict__ x, u8* __restrict__ xt) {
  __shared__ u8 tile[128][36];
  int b = blockIdx.x;            // 32 n * 98 s-chunks
  int n = b / 98;
  int s0 = (b - n * 98) * 32;
  int t = threadIdx.x;
  int tx = t & 31, ty = t >> 5;  // ty in [0,8)
  const float* xb = x + (size_t)n * CIN * SP;
#pragma unroll
  for (int i = 0; i < 16; ++i) {
    int c = ty + (i << 3);                      // 0..127
    tile[c][tx] = sgn_i8(xb[(size_t)c * SP + s0 + tx]);
  }
  __syncthreads();
  int s = t >> 3, cg = t & 7;                   // s 0..31, cg 0..7
  int c0 = cg << 4;
  uint32_t pk[4];
#pragma unroll
  for (int jj = 0; jj < 4; ++jj) {
    uint32_t a0 = tile[c0 + jj * 4 + 0][s];
    uint32_t a1 = tile[c0 + jj * 4 + 1][s];
    uint32_t a2 = tile[c0 + jj * 4 + 2][s];
    uint32_t a3 = tile[c0 + jj * 4 + 3][s];
    pk[jj] = a0 | (a1 << 8) | (a2 << 16) | (a3 << 24);
  }
  u8* dst = xt + (size_t)(n * SP + s0 + s) * CIN + c0;
  uint4 u; u.x = pk[0]; u.y = pk[1]; u.z = pk[2]; u.w = pk[3];
  *(uint4*)dst = u;
}

// ---- main: implicit-GEMM binarized conv, 128x128 tile, i8 MFMA, BK=128,
// ----       512 threads (8 waves, 2Mx4N), dbuf LDS 64KB, 2 blocks/CU ----
__global__ __launch_bounds__(512) void conv_mfma(
    const u8* __restrict__ wT, const u8* __restrict__ xt,
    const float* __restrict__ bias, const u8* __restrict__ zerob,
    float* __restrict__ out) {
  __shared__ u8 As[2][16384];   // [128 rows Cout][128 k] swizzled chunks
  __shared__ u8 Bs[2][16384];   // [128 rows pixel][128 k]

  const int bid = blockIdx.x;
  const int mt = bid & 1;        // Cout tile (0,1)
  const int nt = bid >> 1;       // pixel tile (0..783)
  const int t  = threadIdx.x;
  const int wv = t >> 6;         // 0..7
  const int ln = t & 63;
  const int pb = nt << 7;

  // ---- staging lane geometry: per gl_lds call a wave covers 8 rows x 128B ----
  const int sr  = ln >> 3;            // row-within-8
  const int ch  = ln & 7;             // physical dest chunk
  const int chs = ch ^ sr;            // pre-swizzled source chunk

  const u8* gA[2];
  const u8* gB[2];
  int hh[2], ww[2];
  int ldsOff[2];
#pragma unroll
  for (int call = 0; call < 2; ++call) {
    const int row = call * 64 + wv * 8 + sr;         // 0..127
    ldsOff[call] = (call * 64 + wv * 8) << 7;        // wave-uniform
    gA[call] = wT + (size_t)((mt << 7) + row) * KTOT + (chs << 4);
    const int p = pb + row;
    const int s = p % SP;
    hh[call] = s / HW;
    ww[call] = s - (s / HW) * HW;
    gB[call] = xt + (size_t)p * CIN + (chs << 4);
  }

  // ---- fragment-read geometry (swizzled) ----
  const int wm = wv >> 2, wn = wv & 3;
  const int lr = ln & 15, kg = ln >> 4;
  const int xr = lr & 7;
  const int rdA0 = (((wm << 6) + lr) << 7) + ((kg ^ xr) << 4);
  const int rdA1 = (((wm << 6) + lr) << 7) + (((4 | kg) ^ xr) << 4);
  const int rdB0 = (((wn << 5) + lr) << 7) + ((kg ^ xr) << 4);
  const int rdB1 = (((wn << 5) + lr) << 7) + (((4 | kg) ^ xr) << 4);

  i32x4 acc[4][2];
#pragma unroll
  for (int i = 0; i < 4; ++i)
#pragma unroll
    for (int j = 0; j < 2; ++j) acc[i][j] = (i32x4){0, 0, 0, 0};

  auto stage = [&](int buf, int q) {
    const int dh = q / 3 - 1;           // compile-time after unroll
    const int dw = q - (q / 3) * 3 - 1;
    const int doff = (dh * HW + dw) * CIN;
#pragma unroll
    for (int call = 0; call < 2; ++call) {
      gl_lds16(gA[call] + q * CIN, &As[buf][ldsOff[call]]);
      bool ok = ((unsigned)(hh[call] + dh) < HW) && ((unsigned)(ww[call] + dw) < HW);
      const u8* src = ok ? (gB[call] + doff) : zerob;
      gl_lds16(src, &Bs[buf][ldsOff[call]]);
    }
  };

  stage(0, 0);
#pragma unroll
  for (int s = 0; s < 9; ++s) {
    __syncthreads();                    // drains vmcnt -> buf s&1 ready
    if (s + 1 < 9) stage((s + 1) & 1, s + 1);
    const int buf = s & 1;
#pragma unroll
    for (int kc = 0; kc < 2; ++kc) {
      i32x4 af[4], bfg[2];
#pragma unroll
      for (int i = 0; i < 4; ++i)
        af[i] = *(const i32x4*)&As[buf][(kc ? rdA1 : rdA0) + (i << 11)];
#pragma unroll
      for (int j = 0; j < 2; ++j)
        bfg[j] = *(const i32x4*)&Bs[buf][(kc ? rdB1 : rdB0) + (j << 11)];
#pragma unroll
      for (int i = 0; i < 4; ++i)
#pragma unroll
        for (int j = 0; j < 2; ++j)
          acc[i][j] = __builtin_amdgcn_mfma_i32_16x16x64_i8(af[i], bfg[j], acc[i][j], 0, 0, 0);
    }
  }

  // ---- epilogue: C[m][n] -> out[nimg][m][sp], + sign(bias[m]) ----
  const int mBase = (mt << 7) + (wm << 6);
  const int nBase = pb + (wn << 5);
#pragma unroll
  for (int j = 0; j < 2; ++j) {
    const int np = nBase + (j << 4) + lr;
    const int nimg = np / SP;
    const int sp = np - nimg * SP;
    float* op = out + (size_t)nimg * COUT * SP + sp;
#pragma unroll
    for (int i = 0; i < 4; ++i) {
      const int m0 = mBase + (i << 4) + (kg << 2);
#pragma unroll
      for (int r = 0; r < 4; ++r) {
        const int m = m0 + r;
        float bv = bias[m];
        float sb = bv > 0.f ? 1.f : (bv < 0.f ? -1.f : 0.f);
        op[(size_t)m * SP] = (float)acc[i][j][r] + sb;
      }
    }
  }
}

// ---- fallback if workspace is too small: direct conv (slow but correct) ----
__global__ void conv_naive(const float* __restrict__ x, const float* __restrict__ w,
                           const float* __restrict__ bias, float* __restrict__ out) {
  int idx = blockIdx.x * 256 + threadIdx.x;
  const int total = NIMG * COUT * SP;
  if (idx >= total) return;
  int sp = idx % SP;
  int o  = (idx / SP) % COUT;
  int n  = idx / (SP * COUT);
  int h = sp / HW, wx = sp - (sp / HW) * HW;
  float acc = 0.f;
  for (int c = 0; c < CIN; ++c) {
    const float* xp = x + (size_t)(n * CIN + c) * SP;
    const float* wp = w + (size_t)(o * CIN + c) * 9;
    for (int kh = 0; kh < 3; ++kh) {
      int hhh = h + kh - 1;
      if ((unsigned)hhh >= HW) continue;
      for (int kw = 0; kw < 3; ++kw) {
        int www = wx + kw - 1;
        if ((unsigned)www >= HW) continue;
        float xv = xp[hhh * HW + www];
        float wv = wp[kh * 3 + kw];
        float xs = xv > 0.f ? 1.f : (xv < 0.f ? -1.f : 0.f);
        float wsn = wv > 0.f ? 1.f : (wv < 0.f ? -1.f : 0.f);
        acc += xs * wsn;
      }
    }
  }
  float bv = bias[o];
  out[idx] = acc + (bv > 0.f ? 1.f : (bv < 0.f ? -1.f : 0.f));
}

extern "C" void kernel_launch(void* const* d_in, const int* in_sizes, int n_in,
                              void* d_out, int out_size, void* d_ws, size_t ws_size,
                              hipStream_t stream) {
  const float* x    = (const float*)d_in[0];
  const float* w    = (const float*)d_in[1];
  const float* bias = (const float*)d_in[2];
  float* out = (float*)d_out;

  const size_t need = (size_t)1048576 + (size_t)NPIX * CIN;  // ~13.9 MB
  if (ws_size >= need) {
    u8* zerob = (u8*)d_ws;                        // 256 B zeros
    u8* wT8   = (u8*)((char*)d_ws + 512);         // 256x1152 i8
    u8* xt8   = (u8*)((char*)d_ws + 1048576);     // NHWC i8
    prep_w<<<(COUT * KTOT + 255) / 256, 256, 0, stream>>>(w, wT8, zerob);
    prep_x<<<NIMG * 98, 256, 0, stream>>>(x, xt8);
    conv_mfma<<<2 * (NPIX / 128), 512, 0, stream>>>(wT8, xt8, bias, zerob, out);
  } else {
    const int total = NIMG * COUT * SP;
    conv_naive<<<(total + 255) / 256, 256, 0, stream>>>(x, w, bias, out);
  }
}

// Round 4
// 65.342 us; speedup vs baseline: 2.0725x; 1.0176x over previous
//
#include <hip/hip_runtime.h>
#include <stdint.h>

#define CIN   128
#define COUT  256
#define HW    56
#define SP    3136      // 56*56
#define NIMG  32
#define NPIX  (NIMG*SP) // 100352
#define KTOT  (CIN*9)   // 1152

typedef unsigned short u16;
typedef unsigned char  u8;
using i32x4 = __attribute__((ext_vector_type(4))) int;

__device__ __forceinline__ u8 sgn_i8(float v) {
  return v > 0.f ? (u8)1 : (v < 0.f ? (u8)0xFF : (u8)0);
}

__device__ __forceinline__ void gl_lds16(const void* g, void* l) {
  __builtin_amdgcn_global_load_lds(
      (const __attribute__((address_space(1))) void*)g,
      (__attribute__((address_space(3))) void*)l, 16, 0, 0);
}

// ---- prepass: binarize + K-transpose weights to i8: wT[o][q*128+c] ----
__global__ void prep_w(const float* __restrict__ w, u8* __restrict__ wT,
                       u8* __restrict__ zerob) {
  int idx = blockIdx.x * 256 + threadIdx.x;
  if (blockIdx.x == 0 && threadIdx.x < 64) ((uint32_t*)zerob)[threadIdx.x] = 0;
  if (idx >= COUT * KTOT) return;
  int o = idx / KTOT;
  int r = idx - o * KTOT;
  int q = r >> 7;
  int c = r & 127;
  wT[idx] = sgn_i8(w[(size_t)(o * CIN + c) * 9 + q]);
}

// ---- prepass: binarize + NCHW->NHWC transpose of x into i8 ----
__global__ void prep_x(const float* __restrict__ x, u8* __restrict__ xt) {
  __shared__ u8 tile[128][36];
  int b = blockIdx.x;            // 32 n * 98 s-chunks
  int n = b / 98;
  int s0 = (b - n * 98) * 32;
  int t = threadIdx.x;
  int tx = t & 31, ty = t >> 5;  // ty in [0,8)
  const float* xb = x + (size_t)n * CIN * SP;
#pragma unroll
  for (int i = 0; i < 16; ++i) {
    int c = ty + (i << 3);                      // 0..127
    tile[c][tx] = sgn_i8(xb[(size_t)c * SP + s0 + tx]);
  }
  __syncthreads();
  int s = t >> 3, cg = t & 7;                   // s 0..31, cg 0..7
  int c0 = cg << 4;
  uint32_t pk[4];
#pragma unroll
  for (int jj = 0; jj < 4; ++jj) {
    uint32_t a0 = tile[c0 + jj * 4 + 0][s];
    uint32_t a1 = tile[c0 + jj * 4 + 1][s];
    uint32_t a2 = tile[c0 + jj * 4 + 2][s];
    uint32_t a3 = tile[c0 + jj * 4 + 3][s];
    pk[jj] = a0 | (a1 << 8) | (a2 << 16) | (a3 << 24);
  }
  u8* dst = xt + (size_t)(n * SP + s0 + s) * CIN + c0;
  uint4 u; u.x = pk[0]; u.y = pk[1]; u.z = pk[2]; u.w = pk[3];
  *(uint4*)dst = u;
}

// ---- main: implicit-GEMM binarized conv, 128x128 tile, i8 MFMA, BK=128,
// ----       512 threads (8 waves, 2Mx4N), dbuf LDS 64KB, 2 blocks/CU,
// ----       XCD-chunked tile swizzle (1568 % 8 == 0 -> bijective) ----
__global__ __launch_bounds__(512) void conv_mfma(
    const u8* __restrict__ wT, const u8* __restrict__ xt,
    const float* __restrict__ bias, const u8* __restrict__ zerob,
    float* __restrict__ out) {
  __shared__ u8 As[2][16384];   // [128 rows Cout][128 k] swizzled chunks
  __shared__ u8 Bs[2][16384];   // [128 rows pixel][128 k]

  // XCD swizzle: consecutive hardware bids round-robin across 8 XCDs.
  // Give each XCD a contiguous chunk of 196 tiles so its resident blocks
  // share a contiguous xt slice (L2-resident) and mt-pairs stay together.
  const int bid0 = blockIdx.x;
  const int bid  = (bid0 & 7) * 196 + (bid0 >> 3);
  const int mt = bid & 1;        // Cout tile (0,1)
  const int nt = bid >> 1;       // pixel tile (0..783)
  const int t  = threadIdx.x;
  const int wv = t >> 6;         // 0..7
  const int ln = t & 63;
  const int pb = nt << 7;

  // ---- staging lane geometry: per gl_lds call a wave covers 8 rows x 128B ----
  const int sr  = ln >> 3;            // row-within-8
  const int ch  = ln & 7;             // physical dest chunk
  const int chs = ch ^ sr;            // pre-swizzled source chunk

  const u8* gA[2];
  const u8* gB[2];
  int hh[2], ww[2];
  int ldsOff[2];
#pragma unroll
  for (int call = 0; call < 2; ++call) {
    const int row = call * 64 + wv * 8 + sr;         // 0..127
    ldsOff[call] = (call * 64 + wv * 8) << 7;        // wave-uniform
    gA[call] = wT + (size_t)((mt << 7) + row) * KTOT + (chs << 4);
    const int p = pb + row;
    const int s = p % SP;
    hh[call] = s / HW;
    ww[call] = s - (s / HW) * HW;
    gB[call] = xt + (size_t)p * CIN + (chs << 4);
  }

  // ---- fragment-read geometry (swizzled) ----
  const int wm = wv >> 2, wn = wv & 3;
  const int lr = ln & 15, kg = ln >> 4;
  const int xr = lr & 7;
  const int rdA0 = (((wm << 6) + lr) << 7) + ((kg ^ xr) << 4);
  const int rdA1 = (((wm << 6) + lr) << 7) + (((4 | kg) ^ xr) << 4);
  const int rdB0 = (((wn << 5) + lr) << 7) + ((kg ^ xr) << 4);
  const int rdB1 = (((wn << 5) + lr) << 7) + (((4 | kg) ^ xr) << 4);

  i32x4 acc[4][2];
#pragma unroll
  for (int i = 0; i < 4; ++i)
#pragma unroll
    for (int j = 0; j < 2; ++j) acc[i][j] = (i32x4){0, 0, 0, 0};

  auto stage = [&](int buf, int q) {
    const int dh = q / 3 - 1;           // compile-time after unroll
    const int dw = q - (q / 3) * 3 - 1;
    const int doff = (dh * HW + dw) * CIN;
#pragma unroll
    for (int call = 0; call < 2; ++call) {
      gl_lds16(gA[call] + q * CIN, &As[buf][ldsOff[call]]);
      bool ok = ((unsigned)(hh[call] + dh) < HW) && ((unsigned)(ww[call] + dw) < HW);
      const u8* src = ok ? (gB[call] + doff) : zerob;
      gl_lds16(src, &Bs[buf][ldsOff[call]]);
    }
  };

  stage(0, 0);
#pragma unroll
  for (int s = 0; s < 9; ++s) {
    __syncthreads();                    // drains vmcnt -> buf s&1 ready
    if (s + 1 < 9) stage((s + 1) & 1, s + 1);
    const int buf = s & 1;
#pragma unroll
    for (int kc = 0; kc < 2; ++kc) {
      i32x4 af[4], bfg[2];
#pragma unroll
      for (int i = 0; i < 4; ++i)
        af[i] = *(const i32x4*)&As[buf][(kc ? rdA1 : rdA0) + (i << 11)];
#pragma unroll
      for (int j = 0; j < 2; ++j)
        bfg[j] = *(const i32x4*)&Bs[buf][(kc ? rdB1 : rdB0) + (j << 11)];
#pragma unroll
      for (int i = 0; i < 4; ++i)
#pragma unroll
        for (int j = 0; j < 2; ++j)
          acc[i][j] = __builtin_amdgcn_mfma_i32_16x16x64_i8(af[i], bfg[j], acc[i][j], 0, 0, 0);
    }
  }

  // ---- epilogue: C[m][n] -> out[nimg][m][sp], + sign(bias[m]) ----
  const int mBase = (mt << 7) + (wm << 6);
  const int nBase = pb + (wn << 5);
#pragma unroll
  for (int j = 0; j < 2; ++j) {
    const int np = nBase + (j << 4) + lr;
    const int nimg = np / SP;
    const int sp = np - nimg * SP;
    float* op = out + (size_t)nimg * COUT * SP + sp;
#pragma unroll
    for (int i = 0; i < 4; ++i) {
      const int m0 = mBase + (i << 4) + (kg << 2);
#pragma unroll
      for (int r = 0; r < 4; ++r) {
        const int m = m0 + r;
        float bv = bias[m];
        float sb = bv > 0.f ? 1.f : (bv < 0.f ? -1.f : 0.f);
        op[(size_t)m * SP] = (float)acc[i][j][r] + sb;
      }
    }
  }
}

// ---- fallback if workspace is too small: direct conv (slow but correct) ----
__global__ void conv_naive(const float* __restrict__ x, const float* __restrict__ w,
                           const float* __restrict__ bias, float* __restrict__ out) {
  int idx = blockIdx.x * 256 + threadIdx.x;
  const int total = NIMG * COUT * SP;
  if (idx >= total) return;
  int sp = idx % SP;
  int o  = (idx / SP) % COUT;
  int n  = idx / (SP * COUT);
  int h = sp / HW, wx = sp - (sp / HW) * HW;
  float acc = 0.f;
  for (int c = 0; c < CIN; ++c) {
    const float* xp = x + (size_t)(n * CIN + c) * SP;
    const float* wp = w + (size_t)(o * CIN + c) * 9;
    for (int kh = 0; kh < 3; ++kh) {
      int hhh = h + kh - 1;
      if ((unsigned)hhh >= HW) continue;
      for (int kw = 0; kw < 3; ++kw) {
        int www = wx + kw - 1;
        if ((unsigned)www >= HW) continue;
        float xv = xp[hhh * HW + www];
        float wv = wp[kh * 3 + kw];
        float xs = xv > 0.f ? 1.f : (xv < 0.f ? -1.f : 0.f);
        float wsn = wv > 0.f ? 1.f : (wv < 0.f ? -1.f : 0.f);
        acc += xs * wsn;
      }
    }
  }
  float bv = bias[o];
  out[idx] = acc + (bv > 0.f ? 1.f : (bv < 0.f ? -1.f : 0.f));
}

extern "C" void kernel_launch(void* const* d_in, const int* in_sizes, int n_in,
                              void* d_out, int out_size, void* d_ws, size_t ws_size,
                              hipStream_t stream) {
  const float* x    = (const float*)d_in[0];
  const float* w    = (const float*)d_in[1];
  const float* bias = (const float*)d_in[2];
  float* out = (float*)d_out;

  const size_t need = (size_t)1048576 + (size_t)NPIX * CIN;  // ~13.9 MB
  if (ws_size >= need) {
    u8* zerob = (u8*)d_ws;                        // 256 B zeros
    u8* wT8   = (u8*)((char*)d_ws + 512);         // 256x1152 i8
    u8* xt8   = (u8*)((char*)d_ws + 1048576);     // NHWC i8
    prep_w<<<(COUT * KTOT + 255) / 256, 256, 0, stream>>>(w, wT8, zerob);
    prep_x<<<NIMG * 98, 256, 0, stream>>>(x, xt8);
    conv_mfma<<<2 * (NPIX / 128), 512, 0, stream>>>(wT8, xt8, bias, zerob, out);
  } else {
    const int total = NIMG * COUT * SP;
    conv_naive<<<(total + 255) / 256, 256, 0, stream>>>(x, w, bias, out);
  }
}

// Round 5
// 52.812 us; speedup vs baseline: 2.5642x; 1.2373x over previous
//
#include <hip/hip_runtime.h>
#include <stdint.h>

#define CIN   128
#define COUT  256
#define HW    56
#define SP    3136      // 56*56
#define NIMG  32
#define NPIX  (NIMG*SP) // 100352
#define KTOT  (CIN*9)   // 1152

typedef unsigned short u16;
typedef unsigned char  u8;
using i32x4 = __attribute__((ext_vector_type(4))) int;

__device__ __forceinline__ u8 sgn_i8(float v) {
  return v > 0.f ? (u8)1 : (v < 0.f ? (u8)0xFF : (u8)0);
}

__device__ __forceinline__ void gl_lds16(const void* g, void* l) {
  __builtin_amdgcn_global_load_lds(
      (const __attribute__((address_space(1))) void*)g,
      (__attribute__((address_space(3))) void*)l, 16, 0, 0);
}

// ---- prepass: binarize + K-transpose weights to i8: wT[o][q*128+c] ----
__global__ void prep_w(const float* __restrict__ w, u8* __restrict__ wT,
                       u8* __restrict__ zerob) {
  int idx = blockIdx.x * 256 + threadIdx.x;
  if (blockIdx.x == 0 && threadIdx.x < 64) ((uint32_t*)zerob)[threadIdx.x] = 0;
  if (idx >= COUT * KTOT) return;
  int o = idx / KTOT;
  int r = idx - o * KTOT;
  int q = r >> 7;
  int c = r & 127;
  wT[idx] = sgn_i8(w[(size_t)(o * CIN + c) * 9 + q]);
}

// ---- prepass: binarize + NCHW->NHWC transpose of x into i8 ----
__global__ void prep_x(const float* __restrict__ x, u8* __restrict__ xt) {
  __shared__ u8 tile[128][36];
  int b = blockIdx.x;            // 32 n * 98 s-chunks
  int n = b / 98;
  int s0 = (b - n * 98) * 32;
  int t = threadIdx.x;
  int tx = t & 31, ty = t >> 5;  // ty in [0,8)
  const float* xb = x + (size_t)n * CIN * SP;
#pragma unroll
  for (int i = 0; i < 16; ++i) {
    int c = ty + (i << 3);                      // 0..127
    tile[c][tx] = sgn_i8(xb[(size_t)c * SP + s0 + tx]);
  }
  __syncthreads();
  int s = t >> 3, cg = t & 7;                   // s 0..31, cg 0..7
  int c0 = cg << 4;
  uint32_t pk[4];
#pragma unroll
  for (int jj = 0; jj < 4; ++jj) {
    uint32_t a0 = tile[c0 + jj * 4 + 0][s];
    uint32_t a1 = tile[c0 + jj * 4 + 1][s];
    uint32_t a2 = tile[c0 + jj * 4 + 2][s];
    uint32_t a3 = tile[c0 + jj * 4 + 3][s];
    pk[jj] = a0 | (a1 << 8) | (a2 << 16) | (a3 << 24);
  }
  u8* dst = xt + (size_t)(n * SP + s0 + s) * CIN + c0;
  uint4 u; u.x = pk[0]; u.y = pk[1]; u.z = pk[2]; u.w = pk[3];
  *(uint4*)dst = u;
}

// ---- main: implicit-GEMM binarized conv with LDS halo B-reuse ----
// tile: 128 Cout x 224 pixels (224 = 4 h-rows, image-aligned: 224*14 = 3136).
// B staged ONCE per block as a zero-padded halo [6 vh][58 col][128 cin];
// all 9 taps read it at constant slot offsets. A (wT) staged per tap, dbuf.
// 512 thr = 8 waves (4M x 2N), per-wave 32x112, acc[2][7].
// LDS = 48KB halo + 2x16KB A = 80KB -> 2 blocks/CU.
__global__ __launch_bounds__(512) void conv_mfma(
    const u8* __restrict__ wT, const u8* __restrict__ xt,
    const float* __restrict__ bias, const u8* __restrict__ zerob,
    float* __restrict__ out) {
  __shared__ u8 halo[49152];    // 384 slots x 128 B (348 real)
  __shared__ u8 As[2][16384];   // [128 Cout][128 cin] per tap, swizzled chunks

  // XCD-chunked swizzle (896 = 8*112, bijective); mt pairs stay adjacent.
  const int bid0 = blockIdx.x;
  const int bid  = (bid0 & 7) * 112 + (bid0 >> 3);
  const int mt  = bid & 1;        // Cout half
  const int nt2 = bid >> 1;       // 0..447
  const int n    = nt2 / 14;      // image
  const int hblk = nt2 - n * 14;  // 4-row block
  const int h0   = hblk * 4;
  const int sp0  = hblk * 224;

  const int t  = threadIdx.x;
  const int wv = t >> 6;          // 0..7
  const int ln = t & 63;

  // staging lane geometry: slot/row = t>>3, chunk = t&7, swizzled source chunk
  const int tRow = t >> 3;                  // 0..63
  const int chsA = (t & 7) ^ (tRow & 7);    // source chunk (XOR involution)

  // ---- prologue: stage halo (6 calls x 64 slots) ----
#pragma unroll
  for (int c = 0; c < 6; ++c) {
    const int slot = c * 64 + tRow;         // 0..383
    const int vh  = slot / 58;
    const int col = slot - vh * 58;
    const int gh  = h0 - 1 + vh;
    const bool valid = (slot < 348) && ((unsigned)gh < HW) && (col >= 1) && (col <= 56);
    const u8* src = valid
        ? xt + (((size_t)(n * SP + gh * HW + col - 1)) << 7) + (chsA << 4)
        : zerob;
    gl_lds16(src, &halo[c * 8192 + wv * 1024]);
  }

  // ---- A staging ----
  const u8* wTbase = wT + (size_t)(mt * 128 + tRow) * KTOT + (chsA << 4);
  auto stageA = [&](int b, int q) {
#pragma unroll
    for (int c = 0; c < 2; ++c)
      gl_lds16(wTbase + (size_t)c * 64 * KTOT + q * CIN,
               &As[b][c * 8192 + wv * 1024]);
  };
  stageA(0, 0);

  // ---- fragment geometry ----
  const int wm = wv >> 1, wn = wv & 1;      // 4M x 2N
  const int lr = ln & 15, kg = ln >> 4;
  const int kgs0 = kg << 4;
  const int rdA0 = ((wm * 32 + lr) << 7) + ((kg ^ (lr & 7)) << 4);
  const int rdA1 = rdA0 + (16 << 7);

  int slotj[7];
#pragma unroll
  for (int j = 0; j < 7; ++j) {
    const int px = wn * 112 + j * 16 + lr;  // 0..223
    const int ph = px / 56;
    slotj[j] = (1 + ph) * 58 + (px - ph * 56) + 1;
  }

  i32x4 acc[2][7];
#pragma unroll
  for (int i = 0; i < 2; ++i)
#pragma unroll
    for (int j = 0; j < 7; ++j) acc[i][j] = (i32x4){0, 0, 0, 0};

  constexpr int DC[9] = {-59, -58, -57, -1, 0, 1, 57, 58, 59};

#pragma unroll
  for (int q = 0; q < 9; ++q) {
    __syncthreads();                 // halo + As[q&1] ready
    if (q < 8) stageA((q + 1) & 1, q + 1);
    const int buf = q & 1;
    int ba[7];
#pragma unroll
    for (int j = 0; j < 7; ++j) {
      const int s_t = slotj[j] + DC[q];
      ba[j] = (s_t << 7) + (kgs0 ^ ((s_t & 7) << 4));
    }
#pragma unroll
    for (int kc = 0; kc < 2; ++kc) {
      const i32x4 af0 = *(const i32x4*)&As[buf][rdA0 ^ (kc << 6)];
      const i32x4 af1 = *(const i32x4*)&As[buf][rdA1 ^ (kc << 6)];
#pragma unroll
      for (int j = 0; j < 7; ++j) {
        const i32x4 bf = *(const i32x4*)&halo[ba[j] ^ (kc << 6)];
        acc[0][j] = __builtin_amdgcn_mfma_i32_16x16x64_i8(af0, bf, acc[0][j], 0, 0, 0);
        acc[1][j] = __builtin_amdgcn_mfma_i32_16x16x64_i8(af1, bf, acc[1][j], 0, 0, 0);
      }
    }
  }

  // ---- epilogue: C[m][px] -> out[n][m][sp0+px], + sign(bias[m]) ----
  const int mrow = mt * 128 + wm * 32 + kg * 4;
  float* obase = out + (size_t)n * COUT * SP + sp0 + wn * 112 + lr;
#pragma unroll
  for (int i = 0; i < 2; ++i) {
#pragma unroll
    for (int r = 0; r < 4; ++r) {
      const int m = mrow + i * 16 + r;
      const float bv = bias[m];
      const float sb = bv > 0.f ? 1.f : (bv < 0.f ? -1.f : 0.f);
      float* op = obase + (size_t)m * SP;
#pragma unroll
      for (int j = 0; j < 7; ++j)
        op[j * 16] = (float)acc[i][j][r] + sb;
    }
  }
}

// ---- fallback if workspace is too small: direct conv (slow but correct) ----
__global__ void conv_naive(const float* __restrict__ x, const float* __restrict__ w,
                           const float* __restrict__ bias, float* __restrict__ out) {
  int idx = blockIdx.x * 256 + threadIdx.x;
  const int total = NIMG * COUT * SP;
  if (idx >= total) return;
  int sp = idx % SP;
  int o  = (idx / SP) % COUT;
  int nn = idx / (SP * COUT);
  int h = sp / HW, wx = sp - (sp / HW) * HW;
  float acc = 0.f;
  for (int c = 0; c < CIN; ++c) {
    const float* xp = x + (size_t)(nn * CIN + c) * SP;
    const float* wp = w + (size_t)(o * CIN + c) * 9;
    for (int kh = 0; kh < 3; ++kh) {
      int hhh = h + kh - 1;
      if ((unsigned)hhh >= HW) continue;
      for (int kw = 0; kw < 3; ++kw) {
        int www = wx + kw - 1;
        if ((unsigned)www >= HW) continue;
        float xv = xp[hhh * HW + www];
        float wv = wp[kh * 3 + kw];
        float xs = xv > 0.f ? 1.f : (xv < 0.f ? -1.f : 0.f);
        float wsn = wv > 0.f ? 1.f : (wv < 0.f ? -1.f : 0.f);
        acc += xs * wsn;
      }
    }
  }
  float bv = bias[o];
  out[idx] = acc + (bv > 0.f ? 1.f : (bv < 0.f ? -1.f : 0.f));
}

extern "C" void kernel_launch(void* const* d_in, const int* in_sizes, int n_in,
                              void* d_out, int out_size, void* d_ws, size_t ws_size,
                              hipStream_t stream) {
  const float* x    = (const float*)d_in[0];
  const float* w    = (const float*)d_in[1];
  const float* bias = (const float*)d_in[2];
  float* out = (float*)d_out;

  const size_t need = (size_t)1048576 + (size_t)NPIX * CIN;  // ~13.9 MB
  if (ws_size >= need) {
    u8* zerob = (u8*)d_ws;                        // 256 B zeros
    u8* wT8   = (u8*)((char*)d_ws + 512);         // 256x1152 i8
    u8* xt8   = (u8*)((char*)d_ws + 1048576);     // NHWC i8
    prep_w<<<(COUT * KTOT + 255) / 256, 256, 0, stream>>>(w, wT8, zerob);
    prep_x<<<NIMG * 98, 256, 0, stream>>>(x, xt8);
    conv_mfma<<<896, 512, 0, stream>>>(wT8, xt8, bias, zerob, out);
  } else {
    const int total = NIMG * COUT * SP;
    conv_naive<<<(total + 255) / 256, 256, 0, stream>>>(x, w, bias, out);
  }
}